// Round 10
// baseline (266.044 us; speedup 1.0000x reference)
//
#include <hip/hip_runtime.h>

#define NHEADS 4
#define HDIM   64
#define BATCH  8
#define SEQ    1024
#define CH     256   // H*hd = in_dim = out_dim
#define LOG2E  1.4426950408889634f
#define MC     128           // m-chunk per staging step (attn4)
#define NC     (SEQ / MC)    // 8 chunks
#define LDP    132           // LDS row stride in floats

typedef float  f32x4  __attribute__((ext_vector_type(4)));
typedef __bf16 bf16x8 __attribute__((ext_vector_type(8)));
typedef short  s16x8  __attribute__((ext_vector_type(8)));
union FU { s16x8 s; bf16x8 b; };

__device__ inline unsigned short f2bf(float f) {
    unsigned u = __float_as_uint(f);
    return (unsigned short)((u + 0x7fffu + ((u >> 16) & 1u)) >> 16);
}

// ---------------------------------------------------------------------------
// K0: WpT[ch][k] = bf16(Wp[k][ch])
// ---------------------------------------------------------------------------
__global__ __launch_bounds__(256) void wpt_cast(const float* __restrict__ Wp,
                                                unsigned short* __restrict__ WpT) {
    __shared__ float T[32][33];
    const int t = threadIdx.x;
    const int kt = blockIdx.x * 32, ct = blockIdx.y * 32;
    const int r = t >> 3, c4 = (t & 7) * 4;
    float4 v = *reinterpret_cast<const float4*>(&Wp[(size_t)(kt + r) * CH + ct + c4]);
    T[r][c4 + 0] = v.x; T[r][c4 + 1] = v.y; T[r][c4 + 2] = v.z; T[r][c4 + 3] = v.w;
    __syncthreads();
    unsigned p0 = (unsigned)f2bf(T[c4 + 0][r]) | ((unsigned)f2bf(T[c4 + 1][r]) << 16);
    unsigned p1 = (unsigned)f2bf(T[c4 + 2][r]) | ((unsigned)f2bf(T[c4 + 3][r]) << 16);
    uint2 o = make_uint2(p0, p1);
    *reinterpret_cast<uint2*>(&WpT[(size_t)(ct + r) * CH + kt + c4]) = o;
}

// ---------------------------------------------------------------------------
// K1: projT = (x @ Wp)^T via MFMA. Block = 16 x-rows (R6 version, grid 512).
// ---------------------------------------------------------------------------
__global__ __launch_bounds__(256) void proj_fused(const float* __restrict__ x,
                                                  const unsigned short* __restrict__ WpT,
                                                  const float* __restrict__ Ws,
                                                  unsigned short* __restrict__ projT,
                                                  float* __restrict__ sl,
                                                  float* __restrict__ sr) {
    const int t = threadIdx.x, w = t >> 6, l = t & 63, il = l & 15, g = l >> 4;
    const int row0 = blockIdx.x * 16;
    const int b = row0 >> 10, n0 = row0 & 1023;

    const unsigned short* Ap = WpT + (size_t)(w * 64 + il) * CH + g * 8;
    const float*          Bp = x + (size_t)(row0 + il) * CH + g * 8;

    f32x4 acc[4] = {};
#pragma unroll
    for (int kt = 0; kt < 8; ++kt) {
        FU a[4], bb;
#pragma unroll
        for (int ai = 0; ai < 4; ++ai)
            a[ai].s = *reinterpret_cast<const s16x8*>(Ap + (size_t)ai * 16 * CH + kt * 32);
        float4 v0 = *reinterpret_cast<const float4*>(Bp + kt * 32);
        float4 v1 = *reinterpret_cast<const float4*>(Bp + kt * 32 + 4);
        bb.b[0] = (__bf16)v0.x; bb.b[1] = (__bf16)v0.y;
        bb.b[2] = (__bf16)v0.z; bb.b[3] = (__bf16)v0.w;
        bb.b[4] = (__bf16)v1.x; bb.b[5] = (__bf16)v1.y;
        bb.b[6] = (__bf16)v1.z; bb.b[7] = (__bf16)v1.w;
#pragma unroll
        for (int ai = 0; ai < 4; ++ai)
            acc[ai] = __builtin_amdgcn_mfma_f32_16x16x32_bf16(a[ai].b, bb.b, acc[ai], 0, 0, 0);
    }

    unsigned short* pTb = projT + ((size_t)(b * NHEADS + w) * HDIM) * SEQ + n0 + il;
#pragma unroll
    for (int ai = 0; ai < 4; ++ai)
#pragma unroll
        for (int q = 0; q < 4; ++q)
            pTb[(size_t)(ai * 16 + g * 4 + q) * SEQ] = f2bf(acc[ai][q]);

    float pl = 0.f, pr = 0.f;
#pragma unroll
    for (int ai = 0; ai < 4; ++ai) {
        float4 wlv = *reinterpret_cast<const float4*>(&Ws[ai * 16 + g * 4]);
        float4 wrv = *reinterpret_cast<const float4*>(&Ws[HDIM + ai * 16 + g * 4]);
        pl += acc[ai][0] * wlv.x + acc[ai][1] * wlv.y + acc[ai][2] * wlv.z + acc[ai][3] * wlv.w;
        pr += acc[ai][0] * wrv.x + acc[ai][1] * wrv.y + acc[ai][2] * wrv.z + acc[ai][3] * wrv.w;
    }
    pl += __shfl_xor(pl, 16); pl += __shfl_xor(pl, 32);
    pr += __shfl_xor(pr, 16); pr += __shfl_xor(pr, 32);
    if (l < 16) {
        sl[(size_t)(b * NHEADS + w) * SEQ + n0 + il] = pl * LOG2E;
        sr[(size_t)(b * NHEADS + w) * SEQ + n0 + il] = pr * LOG2E;
    }
}

// ---------------------------------------------------------------------------
// K3: production attention = R6's attn4 (best so far, 52.7us incl fused copy)
// ---------------------------------------------------------------------------
template <bool FUSE_ADJ>
__global__ __launch_bounds__(256, 2) void attn4(const float* __restrict__ x,
                                                const float* __restrict__ adj,
                                                const unsigned short* __restrict__ projT,
                                                const float* __restrict__ sl,
                                                const float* __restrict__ sr,
                                                const float* __restrict__ Ws,
                                                const float* __restrict__ bias,
                                                float* __restrict__ out,
                                                float* __restrict__ out_adj) {
    __shared__ __align__(16) float abuf[2][16][LDP];

    const int t = threadIdx.x;
    const int h = t >> 6, l = t & 63, il = l & 15, g = l >> 4;
    const int i0 = blockIdx.x * 16;
    const int b  = blockIdx.y;
    const float wa2 = Ws[2 * HDIM] * LOG2E;

    const int str = t >> 4;
    const int stc = (t & 15) * 4;
    const size_t astg = ((size_t)(b * SEQ + i0 + str)) * SEQ + stc;

    const float sl_i = sl[(size_t)(b * NHEADS + h) * SEQ + i0 + il];
    const float* srp = sr + (size_t)(b * NHEADS + h) * SEQ;
    const unsigned short* pT = projT + ((size_t)(b * NHEADS + h) * HDIM + il) * SEQ + g * 8;

    FU ones;
#pragma unroll
    for (int j = 0; j < 8; ++j) ones.s[j] = (short)0x3F80;

    f32x4 acc[4] = {};
    f32x4 dacc = {};

    float4 c00 = *reinterpret_cast<const float4*>(adj + astg);
    float4 c01 = *reinterpret_cast<const float4*>(adj + astg + 64);
    float4 cur0 = *reinterpret_cast<const float4*>(adj + astg + MC);
    float4 cur1 = *reinterpret_cast<const float4*>(adj + astg + MC + 64);
    if (FUSE_ADJ) {
        *reinterpret_cast<float4*>(out_adj + astg)      = c00;
        *reinterpret_cast<float4*>(out_adj + astg + 64) = c01;
    }
    *reinterpret_cast<float4*>(&abuf[0][str][stc])      = c00;
    *reinterpret_cast<float4*>(&abuf[0][str][stc + 64]) = c01;
    __syncthreads();

#pragma unroll 2
    for (int c = 0; c < NC; ++c) {
        float4 nx0 = {}, nx1 = {};
        if (c + 2 < NC) {
            nx0 = *reinterpret_cast<const float4*>(adj + astg + (size_t)(c + 2) * MC);
            nx1 = *reinterpret_cast<const float4*>(adj + astg + (size_t)(c + 2) * MC + 64);
        }
        const float* aT = &abuf[c & 1][il][0];
        const int mt = c * MC;
#pragma unroll
        for (int kq = 0; kq < 4; ++kq) {
            const int mk = kq * 32 + g * 8;
            float4 a0 = *reinterpret_cast<const float4*>(aT + mk);
            float4 a1 = *reinterpret_cast<const float4*>(aT + mk + 4);
            float4 s0 = *reinterpret_cast<const float4*>(srp + mt + mk);
            float4 s1 = *reinterpret_cast<const float4*>(srp + mt + mk + 4);
            float aj[8] = {a0.x, a0.y, a0.z, a0.w, a1.x, a1.y, a1.z, a1.w};
            float sv[8] = {s0.x, s0.y, s0.z, s0.w, s1.x, s1.y, s1.z, s1.w};
            FU af;
#pragma unroll
            for (int j = 0; j < 8; ++j) {
                float s = fmaf(aj[j], wa2, sl_i + sv[j]);
                s = __builtin_amdgcn_fmed3f(s, 0.2f * s, 86.5617f);
                float e = (aj[j] <= 1e-5f) ? 0.f : __builtin_amdgcn_exp2f(s);
                af.b[j] = (__bf16)e;
            }
            FU b0, b1, b2, b3;
            b0.s = *reinterpret_cast<const s16x8*>(pT + mt + kq * 32);
            b1.s = *reinterpret_cast<const s16x8*>(pT + mt + kq * 32 + (size_t)16 * SEQ);
            b2.s = *reinterpret_cast<const s16x8*>(pT + mt + kq * 32 + (size_t)32 * SEQ);
            b3.s = *reinterpret_cast<const s16x8*>(pT + mt + kq * 32 + (size_t)48 * SEQ);
            acc[0] = __builtin_amdgcn_mfma_f32_16x16x32_bf16(af.b, b0.b, acc[0], 0, 0, 0);
            acc[1] = __builtin_amdgcn_mfma_f32_16x16x32_bf16(af.b, b1.b, acc[1], 0, 0, 0);
            acc[2] = __builtin_amdgcn_mfma_f32_16x16x32_bf16(af.b, b2.b, acc[2], 0, 0, 0);
            acc[3] = __builtin_amdgcn_mfma_f32_16x16x32_bf16(af.b, b3.b, acc[3], 0, 0, 0);
            dacc   = __builtin_amdgcn_mfma_f32_16x16x32_bf16(af.b, ones.b, dacc, 0, 0, 0);
        }
        if (c + 1 < NC) {
            if (FUSE_ADJ) {
                *reinterpret_cast<float4*>(out_adj + astg + (size_t)(c + 1) * MC)      = cur0;
                *reinterpret_cast<float4*>(out_adj + astg + (size_t)(c + 1) * MC + 64) = cur1;
            }
            *reinterpret_cast<float4*>(&abuf[(c + 1) & 1][str][stc])      = cur0;
            *reinterpret_cast<float4*>(&abuf[(c + 1) & 1][str][stc + 64]) = cur1;
        }
        __syncthreads();
        cur0 = nx0; cur1 = nx1;
    }

    const float* bb = bias + h * HDIM;
#pragma unroll
    for (int q = 0; q < 4; ++q) {
        const float inv = 1.f / dacc[q];
        const size_t ob = ((size_t)(b * SEQ + i0 + g * 4 + q)) * CH + h * HDIM + il;
#pragma unroll
        for (int bj = 0; bj < 4; ++bj) {
            float v = fmaf(acc[bj][q], inv, x[ob + bj * 16] + bb[bj * 16 + il]);
            out[ob + bj * 16] = fmaxf(v, 0.5f * v);
        }
    }
}

// ---------------------------------------------------------------------------
// ABLATION kernels (diagnostic; write to d_ws scratch only).
// Clone of attn5's no-barrier loop with ONE knob removed per variant:
//   V=0 full | V=1 no adj loads | V=2 no e-chain | V=3 no projT loads |
//   V=4 no MFMA (keep loads+e via xor keep-alive, rule #17)
// ---------------------------------------------------------------------------
template <int V>
__global__ __launch_bounds__(512, 4) void abl(const float* __restrict__ adj,
                                              const unsigned short* __restrict__ projT,
                                              const float* __restrict__ sl,
                                              const float* __restrict__ sr,
                                              const float* __restrict__ Ws,
                                              float* __restrict__ dbg) {
    const int t = threadIdx.x;
    const int w = t >> 6, l = t & 63, il = l & 15, g = l >> 4;
    const int h = w & 3, mh = w >> 2;
    const int i0 = blockIdx.x * 16;
    const int b  = blockIdx.y;
    const float wa2 = Ws[2 * HDIM] * LOG2E;

    const float sl_i = sl[(size_t)(b * NHEADS + h) * SEQ + i0 + il];
    const float* srp = sr + (size_t)(b * NHEADS + h) * SEQ + mh * 512;
    const unsigned short* pT = projT + ((size_t)(b * NHEADS + h) * HDIM + il) * SEQ + mh * 512 + g * 8;
    const size_t arow = ((size_t)(b * SEQ + i0 + il)) * SEQ + mh * 512 + g * 8;

    FU ones;
#pragma unroll
    for (int j = 0; j < 8; ++j) ones.s[j] = (short)0x3F80;

    f32x4 acc[4] = {};
    f32x4 dacc = {};
    int keep = 0;

    for (int s2 = 0; s2 < 8; ++s2) {
        const int mt0 = s2 * 64;
        float4 A[2][2], S[2][2];
#pragma unroll
        for (int u = 0; u < 2; ++u) {
            const int mt = mt0 + u * 32;
            if (V != 1) {
                A[u][0] = *reinterpret_cast<const float4*>(adj + arow + mt);
                A[u][1] = *reinterpret_cast<const float4*>(adj + arow + mt + 4);
            }
            S[u][0] = *reinterpret_cast<const float4*>(srp + mt + g * 8);
            S[u][1] = *reinterpret_cast<const float4*>(srp + mt + g * 8 + 4);
        }
#pragma unroll
        for (int u = 0; u < 2; ++u) {
            const int mt = mt0 + u * 32;
            FU b0, b1, b2, b3;
            if (V != 3) {
                b0.s = *reinterpret_cast<const s16x8*>(pT + mt);
                b1.s = *reinterpret_cast<const s16x8*>(pT + mt + (size_t)16 * SEQ);
                b2.s = *reinterpret_cast<const s16x8*>(pT + mt + (size_t)32 * SEQ);
                b3.s = *reinterpret_cast<const s16x8*>(pT + mt + (size_t)48 * SEQ);
            } else {
                b0 = ones; b1 = ones; b2 = ones; b3 = ones;
            }
            float sv[8] = {S[u][0].x, S[u][0].y, S[u][0].z, S[u][0].w,
                           S[u][1].x, S[u][1].y, S[u][1].z, S[u][1].w};
            float aj[8];
            if (V != 1) {
                aj[0] = A[u][0].x; aj[1] = A[u][0].y; aj[2] = A[u][0].z; aj[3] = A[u][0].w;
                aj[4] = A[u][1].x; aj[5] = A[u][1].y; aj[6] = A[u][1].z; aj[7] = A[u][1].w;
            } else {
#pragma unroll
                for (int j = 0; j < 8; ++j) aj[j] = sv[j];   // reuse sr as pseudo-adj
            }
            FU af;
#pragma unroll
            for (int j = 0; j < 8; ++j) {
                if (V == 2) {
                    af.b[j] = (__bf16)aj[j];                 // e-chain removed
                } else {
                    float s = fmaf(aj[j], wa2, sl_i + sv[j]);
                    s = __builtin_amdgcn_fmed3f(s, 0.2f * s, 86.5617f);
                    float e = (aj[j] <= 1e-5f) ? 0.f : __builtin_amdgcn_exp2f(s);
                    af.b[j] = (__bf16)e;
                }
            }
            if (V == 4) {
                // keep loads + e-chain results live without MFMA (rule #17)
                const int* ap = reinterpret_cast<const int*>(&af);
                keep ^= ap[0] ^ ap[1] ^ ap[2] ^ ap[3];
                const int* bp0 = reinterpret_cast<const int*>(&b0);
                const int* bp1 = reinterpret_cast<const int*>(&b1);
                const int* bp2 = reinterpret_cast<const int*>(&b2);
                const int* bp3 = reinterpret_cast<const int*>(&b3);
                keep ^= bp0[0] ^ bp1[0] ^ bp2[0] ^ bp3[0];
            } else {
                acc[0] = __builtin_amdgcn_mfma_f32_16x16x32_bf16(af.b, b0.b, acc[0], 0, 0, 0);
                acc[1] = __builtin_amdgcn_mfma_f32_16x16x32_bf16(af.b, b1.b, acc[1], 0, 0, 0);
                acc[2] = __builtin_amdgcn_mfma_f32_16x16x32_bf16(af.b, b2.b, acc[2], 0, 0, 0);
                acc[3] = __builtin_amdgcn_mfma_f32_16x16x32_bf16(af.b, b3.b, acc[3], 0, 0, 0);
                dacc   = __builtin_amdgcn_mfma_f32_16x16x32_bf16(af.b, ones.b, dacc, 0, 0, 0);
            }
        }
    }

    float r = acc[0][0] + acc[1][1] + acc[2][2] + acc[3][3] + dacc[0] + (float)keep;
    dbg[((size_t)b * 64 + blockIdx.x) * 512 + t] = r;
}

// ---------------------------------------------------------------------------
// K4 (fallback): copy adj into output chunk 2
// ---------------------------------------------------------------------------
__global__ void adjcopy(const float* __restrict__ adj, float* __restrict__ dst, int n4) {
    int idx = blockIdx.x * blockDim.x + threadIdx.x;
    int stride = gridDim.x * blockDim.x;
    const float4* s = reinterpret_cast<const float4*>(adj);
    float4* d = reinterpret_cast<float4*>(dst);
    for (int i = idx; i < n4; i += stride) d[i] = s[i];
}

extern "C" void kernel_launch(void* const* d_in, const int* in_sizes, int n_in,
                              void* d_out, int out_size, void* d_ws, size_t ws_size,
                              hipStream_t stream) {
    const float* x    = (const float*)d_in[0];
    const float* adj  = (const float*)d_in[1];
    const float* Wp   = (const float*)d_in[2];
    const float* Ws   = (const float*)d_in[3];
    const float* bias = (const float*)d_in[4];
    float* out     = (float*)d_out;
    float* out_adj = out + (size_t)BATCH * SEQ * CH;

    const size_t nProj = (size_t)BATCH * SEQ * CH;
    const size_t nSc   = (size_t)BATCH * NHEADS * SEQ;
    const size_t need  = CH * CH * 2 + nProj * 2 + 2 * nSc * 4;
    const bool use_ws  = (ws_size >= need);
    char* scratch = use_ws ? (char*)d_ws : (char*)out_adj;
    unsigned short* WpT   = (unsigned short*)scratch;
    unsigned short* projT = (unsigned short*)(scratch + (size_t)CH * CH * 2);
    float*          sl    = (float*)(scratch + (size_t)CH * CH * 2 + nProj * 2);
    float*          sr    = sl + nSc;

    wpt_cast<<<dim3(8, 8), 256, 0, stream>>>(Wp, WpT);
    proj_fused<<<dim3(512), 256, 0, stream>>>(x, WpT, Ws, projT, sl, sr);
    if (use_ws) {
        attn4<true><<<dim3(SEQ / 16, BATCH), 256, 0, stream>>>(
            x, adj, projT, sl, sr, Ws, bias, out, out_adj);
        // --- diagnostic ablations into scratch (projT region, rewritten
        //     by proj_fused at the start of every replay -> deterministic) ---
        float* dbg = (float*)projT;
        abl<0><<<dim3(SEQ / 16, BATCH), 512, 0, stream>>>(adj, projT, sl, sr, Ws, dbg);
        abl<1><<<dim3(SEQ / 16, BATCH), 512, 0, stream>>>(adj, projT, sl, sr, Ws, dbg);
        abl<2><<<dim3(SEQ / 16, BATCH), 512, 0, stream>>>(adj, projT, sl, sr, Ws, dbg);
        abl<3><<<dim3(SEQ / 16, BATCH), 512, 0, stream>>>(adj, projT, sl, sr, Ws, dbg);
        abl<4><<<dim3(SEQ / 16, BATCH), 512, 0, stream>>>(adj, projT, sl, sr, Ws, dbg);
    } else {
        attn4<false><<<dim3(SEQ / 16, BATCH), 256, 0, stream>>>(
            x, adj, projT, sl, sr, Ws, bias, out, out_adj);
        adjcopy<<<2048, 256, 0, stream>>>(adj, out_adj, (BATCH * SEQ * SEQ) / 4);
    }
}

// Round 11
// 69.643 us; speedup vs baseline: 3.8201x; 3.8201x over previous
//
#include <hip/hip_runtime.h>

#define NHEADS 4
#define HDIM   64
#define BATCH  8
#define SEQ    1024
#define CH     256   // H*hd = in_dim = out_dim
#define LOG2E  1.4426950408889634f
#define MC     128           // m-chunk per staging step
#define NC     (SEQ / MC)    // 8 chunks
#define LDP    132           // LDS row stride in floats

typedef float  f32x4  __attribute__((ext_vector_type(4)));
typedef __bf16 bf16x8 __attribute__((ext_vector_type(8)));
typedef short  s16x8  __attribute__((ext_vector_type(8)));
union FU { s16x8 s; bf16x8 b; };

__device__ inline unsigned short f2bf(float f) {
    unsigned u = __float_as_uint(f);
    return (unsigned short)((u + 0x7fffu + ((u >> 16) & 1u)) >> 16);
}

// ---------------------------------------------------------------------------
// K0: WpT[ch][k] = bf16(Wp[k][ch])
// ---------------------------------------------------------------------------
__global__ __launch_bounds__(256) void wpt_cast(const float* __restrict__ Wp,
                                                unsigned short* __restrict__ WpT) {
    __shared__ float T[32][33];
    const int t = threadIdx.x;
    const int kt = blockIdx.x * 32, ct = blockIdx.y * 32;
    const int r = t >> 3, c4 = (t & 7) * 4;
    float4 v = *reinterpret_cast<const float4*>(&Wp[(size_t)(kt + r) * CH + ct + c4]);
    T[r][c4 + 0] = v.x; T[r][c4 + 1] = v.y; T[r][c4 + 2] = v.z; T[r][c4 + 3] = v.w;
    __syncthreads();
    unsigned p0 = (unsigned)f2bf(T[c4 + 0][r]) | ((unsigned)f2bf(T[c4 + 1][r]) << 16);
    unsigned p1 = (unsigned)f2bf(T[c4 + 2][r]) | ((unsigned)f2bf(T[c4 + 3][r]) << 16);
    uint2 o = make_uint2(p0, p1);
    *reinterpret_cast<uint2*>(&WpT[(size_t)(ct + r) * CH + kt + c4]) = o;
}

// ---------------------------------------------------------------------------
// K1: projT = (x @ Wp)^T via MFMA. Block = 16 x-rows, wave w = head w.
//     Writes projT bf16 [b][h][d][m] + sl/sr (pre-scaled by log2e).
// ---------------------------------------------------------------------------
__global__ __launch_bounds__(256) void proj_fused(const float* __restrict__ x,
                                                  const unsigned short* __restrict__ WpT,
                                                  const float* __restrict__ Ws,
                                                  unsigned short* __restrict__ projT,
                                                  float* __restrict__ sl,
                                                  float* __restrict__ sr) {
    const int t = threadIdx.x, w = t >> 6, l = t & 63, il = l & 15, g = l >> 4;
    const int row0 = blockIdx.x * 16;
    const int b = row0 >> 10, n0 = row0 & 1023;

    const unsigned short* Ap = WpT + (size_t)(w * 64 + il) * CH + g * 8;
    const float*          Bp = x + (size_t)(row0 + il) * CH + g * 8;

    f32x4 acc[4] = {};
#pragma unroll
    for (int kt = 0; kt < 8; ++kt) {
        FU a[4], bb;
#pragma unroll
        for (int ai = 0; ai < 4; ++ai)
            a[ai].s = *reinterpret_cast<const s16x8*>(Ap + (size_t)ai * 16 * CH + kt * 32);
        float4 v0 = *reinterpret_cast<const float4*>(Bp + kt * 32);
        float4 v1 = *reinterpret_cast<const float4*>(Bp + kt * 32 + 4);
        bb.b[0] = (__bf16)v0.x; bb.b[1] = (__bf16)v0.y;
        bb.b[2] = (__bf16)v0.z; bb.b[3] = (__bf16)v0.w;
        bb.b[4] = (__bf16)v1.x; bb.b[5] = (__bf16)v1.y;
        bb.b[6] = (__bf16)v1.z; bb.b[7] = (__bf16)v1.w;
#pragma unroll
        for (int ai = 0; ai < 4; ++ai)
            acc[ai] = __builtin_amdgcn_mfma_f32_16x16x32_bf16(a[ai].b, bb.b, acc[ai], 0, 0, 0);
    }

    unsigned short* pTb = projT + ((size_t)(b * NHEADS + w) * HDIM) * SEQ + n0 + il;
#pragma unroll
    for (int ai = 0; ai < 4; ++ai)
#pragma unroll
        for (int q = 0; q < 4; ++q)
            pTb[(size_t)(ai * 16 + g * 4 + q) * SEQ] = f2bf(acc[ai][q]);

    float pl = 0.f, pr = 0.f;
#pragma unroll
    for (int ai = 0; ai < 4; ++ai) {
        float4 wlv = *reinterpret_cast<const float4*>(&Ws[ai * 16 + g * 4]);
        float4 wrv = *reinterpret_cast<const float4*>(&Ws[HDIM + ai * 16 + g * 4]);
        pl += acc[ai][0] * wlv.x + acc[ai][1] * wlv.y + acc[ai][2] * wlv.z + acc[ai][3] * wlv.w;
        pr += acc[ai][0] * wrv.x + acc[ai][1] * wrv.y + acc[ai][2] * wrv.z + acc[ai][3] * wrv.w;
    }
    pl += __shfl_xor(pl, 16); pl += __shfl_xor(pl, 32);
    pr += __shfl_xor(pr, 16); pr += __shfl_xor(pr, 32);
    if (l < 16) {
        sl[(size_t)(b * NHEADS + w) * SEQ + n0 + il] = pl * LOG2E;
        sr[(size_t)(b * NHEADS + w) * SEQ + n0 + il] = pr * LOG2E;
    }
}

// ---------------------------------------------------------------------------
// K3: attention (attn4 structure) with XCD-BATCH PARTITIONING:
//     1-D grid of 512; physical block p -> XCD p%8 (round-robin dispatch), so
//     decode b = p%8, ix = p/8. Each XCD then touches ONLY batch b:
//     working set projT[b] (2MB) + sr (16KB) fits its 4MB L2 (was 16MB+ ->
//     L3 thrash at ~400-500cyc/dependent load, the measured ~2000cyc/kq).
// ---------------------------------------------------------------------------
template <bool FUSE_ADJ>
__global__ __launch_bounds__(256, 2) void attn4x(const float* __restrict__ x,
                                                 const float* __restrict__ adj,
                                                 const unsigned short* __restrict__ projT,
                                                 const float* __restrict__ sl,
                                                 const float* __restrict__ sr,
                                                 const float* __restrict__ Ws,
                                                 const float* __restrict__ bias,
                                                 float* __restrict__ out,
                                                 float* __restrict__ out_adj) {
    __shared__ __align__(16) float abuf[2][16][LDP];

    const int t = threadIdx.x;
    const int h = t >> 6, l = t & 63, il = l & 15, g = l >> 4;
    const int b  = blockIdx.x & 7;        // XCD-aligned batch
    const int i0 = (blockIdx.x >> 3) * 16;
    const float wa2 = Ws[2 * HDIM] * LOG2E;

    const int str = t >> 4;
    const int stc = (t & 15) * 4;
    const size_t astg = ((size_t)(b * SEQ + i0 + str)) * SEQ + stc;

    const float sl_i = sl[(size_t)(b * NHEADS + h) * SEQ + i0 + il];
    const float* srp = sr + (size_t)(b * NHEADS + h) * SEQ;
    const unsigned short* pT = projT + ((size_t)(b * NHEADS + h) * HDIM + il) * SEQ + g * 8;

    FU ones;
#pragma unroll
    for (int j = 0; j < 8; ++j) ones.s[j] = (short)0x3F80;

    f32x4 acc[4] = {};
    f32x4 dacc = {};

    float4 c00 = *reinterpret_cast<const float4*>(adj + astg);
    float4 c01 = *reinterpret_cast<const float4*>(adj + astg + 64);
    float4 cur0 = *reinterpret_cast<const float4*>(adj + astg + MC);
    float4 cur1 = *reinterpret_cast<const float4*>(adj + astg + MC + 64);
    if (FUSE_ADJ) {
        *reinterpret_cast<float4*>(out_adj + astg)      = c00;
        *reinterpret_cast<float4*>(out_adj + astg + 64) = c01;
    }
    *reinterpret_cast<float4*>(&abuf[0][str][stc])      = c00;
    *reinterpret_cast<float4*>(&abuf[0][str][stc + 64]) = c01;
    __syncthreads();

#pragma unroll 2
    for (int c = 0; c < NC; ++c) {
        float4 nx0 = {}, nx1 = {};
        if (c + 2 < NC) {
            nx0 = *reinterpret_cast<const float4*>(adj + astg + (size_t)(c + 2) * MC);
            nx1 = *reinterpret_cast<const float4*>(adj + astg + (size_t)(c + 2) * MC + 64);
        }
        const float* aT = &abuf[c & 1][il][0];
        const int mt = c * MC;
#pragma unroll
        for (int kq = 0; kq < 4; ++kq) {
            const int mk = kq * 32 + g * 8;
            float4 a0 = *reinterpret_cast<const float4*>(aT + mk);
            float4 a1 = *reinterpret_cast<const float4*>(aT + mk + 4);
            float4 s0 = *reinterpret_cast<const float4*>(srp + mt + mk);
            float4 s1 = *reinterpret_cast<const float4*>(srp + mt + mk + 4);
            float aj[8] = {a0.x, a0.y, a0.z, a0.w, a1.x, a1.y, a1.z, a1.w};
            float sv[8] = {s0.x, s0.y, s0.z, s0.w, s1.x, s1.y, s1.z, s1.w};
            FU af;
#pragma unroll
            for (int j = 0; j < 8; ++j) {
                float s = fmaf(aj[j], wa2, sl_i + sv[j]);
                s = __builtin_amdgcn_fmed3f(s, 0.2f * s, 86.5617f);
                float e = (aj[j] <= 1e-5f) ? 0.f : __builtin_amdgcn_exp2f(s);
                af.b[j] = (__bf16)e;
            }
            FU b0, b1, b2, b3;
            b0.s = *reinterpret_cast<const s16x8*>(pT + mt + kq * 32);
            b1.s = *reinterpret_cast<const s16x8*>(pT + mt + kq * 32 + (size_t)16 * SEQ);
            b2.s = *reinterpret_cast<const s16x8*>(pT + mt + kq * 32 + (size_t)32 * SEQ);
            b3.s = *reinterpret_cast<const s16x8*>(pT + mt + kq * 32 + (size_t)48 * SEQ);
            acc[0] = __builtin_amdgcn_mfma_f32_16x16x32_bf16(af.b, b0.b, acc[0], 0, 0, 0);
            acc[1] = __builtin_amdgcn_mfma_f32_16x16x32_bf16(af.b, b1.b, acc[1], 0, 0, 0);
            acc[2] = __builtin_amdgcn_mfma_f32_16x16x32_bf16(af.b, b2.b, acc[2], 0, 0, 0);
            acc[3] = __builtin_amdgcn_mfma_f32_16x16x32_bf16(af.b, b3.b, acc[3], 0, 0, 0);
            dacc   = __builtin_amdgcn_mfma_f32_16x16x32_bf16(af.b, ones.b, dacc, 0, 0, 0);
        }
        if (c + 1 < NC) {
            if (FUSE_ADJ) {
                *reinterpret_cast<float4*>(out_adj + astg + (size_t)(c + 1) * MC)      = cur0;
                *reinterpret_cast<float4*>(out_adj + astg + (size_t)(c + 1) * MC + 64) = cur1;
            }
            *reinterpret_cast<float4*>(&abuf[(c + 1) & 1][str][stc])      = cur0;
            *reinterpret_cast<float4*>(&abuf[(c + 1) & 1][str][stc + 64]) = cur1;
        }
        __syncthreads();
        cur0 = nx0; cur1 = nx1;
    }

    const float* bb = bias + h * HDIM;
#pragma unroll
    for (int q = 0; q < 4; ++q) {
        const float inv = 1.f / dacc[q];
        const size_t ob = ((size_t)(b * SEQ + i0 + g * 4 + q)) * CH + h * HDIM + il;
#pragma unroll
        for (int bj = 0; bj < 4; ++bj) {
            float v = fmaf(acc[bj][q], inv, x[ob + bj * 16] + bb[bj * 16 + il]);
            out[ob + bj * 16] = fmaxf(v, 0.5f * v);
        }
    }
}

// ---------------------------------------------------------------------------
// K4 (fallback): copy adj into output chunk 2
// ---------------------------------------------------------------------------
__global__ void adjcopy(const float* __restrict__ adj, float* __restrict__ dst, int n4) {
    int idx = blockIdx.x * blockDim.x + threadIdx.x;
    int stride = gridDim.x * blockDim.x;
    const float4* s = reinterpret_cast<const float4*>(adj);
    float4* d = reinterpret_cast<float4*>(dst);
    for (int i = idx; i < n4; i += stride) d[i] = s[i];
}

extern "C" void kernel_launch(void* const* d_in, const int* in_sizes, int n_in,
                              void* d_out, int out_size, void* d_ws, size_t ws_size,
                              hipStream_t stream) {
    const float* x    = (const float*)d_in[0];
    const float* adj  = (const float*)d_in[1];
    const float* Wp   = (const float*)d_in[2];
    const float* Ws   = (const float*)d_in[3];
    const float* bias = (const float*)d_in[4];
    float* out     = (float*)d_out;
    float* out_adj = out + (size_t)BATCH * SEQ * CH;

    const size_t nProj = (size_t)BATCH * SEQ * CH;
    const size_t nSc   = (size_t)BATCH * NHEADS * SEQ;
    const size_t need  = CH * CH * 2 + nProj * 2 + 2 * nSc * 4;
    const bool use_ws  = (ws_size >= need);
    char* scratch = use_ws ? (char*)d_ws : (char*)out_adj;
    unsigned short* WpT   = (unsigned short*)scratch;
    unsigned short* projT = (unsigned short*)(scratch + (size_t)CH * CH * 2);
    float*          sl    = (float*)(scratch + (size_t)CH * CH * 2 + nProj * 2);
    float*          sr    = sl + nSc;

    wpt_cast<<<dim3(8, 8), 256, 0, stream>>>(Wp, WpT);
    proj_fused<<<dim3(512), 256, 0, stream>>>(x, WpT, Ws, projT, sl, sr);
    if (use_ws) {
        attn4x<true><<<dim3(512), 256, 0, stream>>>(
            x, adj, projT, sl, sr, Ws, bias, out, out_adj);
    } else {
        attn4x<false><<<dim3(512), 256, 0, stream>>>(
            x, adj, projT, sl, sr, Ws, bias, out, out_adj);
        adjcopy<<<2048, 256, 0, stream>>>(adj, out_adj, (BATCH * SEQ * SEQ) / 4);
    }
}